// Round 1
// baseline (707.076 us; speedup 1.0000x reference)
//
#include <hip/hip_runtime.h>
#include <math.h>

#define B_TOT 16384
#define D_TOT 64
#define R_TOT 63
#define H_TOT 256
#define PK_TOT 24
#define TB 32
#define PI_F 3.14159265358979323846f

// Zero x[:,0] and log_det accumulator (atomicAdd target) each call.
__global__ void init_out_kernel(float* __restrict__ out) {
    int b = blockIdx.x * 256 + threadIdx.x;
    if (b < B_TOT) {
        out[b * D_TOT] = 0.0f;                 // x[:,0] = 0
        out[B_TOT * D_TOT + b] = 0.0f;         // log_det = 0
    }
}

// One block: 32 batches x one r. 256 threads (4 waves). 64 KB static LDS -> 2 blocks/CU.
__global__ __launch_bounds__(256, 2) void flow_main(
    const float* __restrict__ z,  const float* __restrict__ W1,
    const float* __restrict__ b1, const float* __restrict__ W2,
    const float* __restrict__ b2, float* __restrict__ out)
{
    const int r   = blockIdx.y;         // 0..62
    const int b0  = blockIdx.x * TB;    // batch tile start
    const int tid = threadIdx.x;

    __shared__ float smem[16384];       // exactly 64 KB
    float* z_t  = smem;                 // [64][32]  z transposed (d-major), 2048 f
    float* h_s  = smem + 2048;          // [32][256] swizzled h, 8192 f
    float* w2t  = smem + 2048 + 8192;   // [24][256] swizzled W2^T, 6144 f
    float* part = w2t;                  // alias after GEMM2: [4][32][24] partials

    // ---------------- stage z tile, transposed ----------------
    #pragma unroll
    for (int it = 0; it < 2; ++it) {
        int idx4 = it * 256 + tid;              // 0..511
        int brow = idx4 >> 4;                   // 0..31
        int dq   = (idx4 & 15) << 2;            // 0..60
        float4 v = *reinterpret_cast<const float4*>(&z[(b0 + brow) * D_TOT + dq]);
        z_t[(dq + 0) * TB + brow] = v.x;
        z_t[(dq + 1) * TB + brow] = v.y;
        z_t[(dq + 2) * TB + brow] = v.z;
        z_t[(dq + 3) * TB + brow] = v.w;
    }
    // ---------------- stage W2^T (granule-swizzled by p&7) ----------------
    #pragma unroll
    for (int it = 0; it < 6; ++it) {
        int idx4 = it * 256 + tid;              // 0..1535
        int k  = idx4 / 6;                      // 0..255
        int pq = (idx4 - k * 6) << 2;           // 0,4,8,12,16,20
        float4 v = *reinterpret_cast<const float4*>(&W2[(r * H_TOT + k) * PK_TOT + pq]);
        int gk = k >> 2, kq = k & 3;
        w2t[(pq + 0) * 256 + (((gk) ^ ((pq + 0) & 7)) << 2) + kq] = v.x;
        w2t[(pq + 1) * 256 + (((gk) ^ ((pq + 1) & 7)) << 2) + kq] = v.y;
        w2t[(pq + 2) * 256 + (((gk) ^ ((pq + 2) & 7)) << 2) + kq] = v.z;
        w2t[(pq + 3) * 256 + (((gk) ^ ((pq + 3) & 7)) << 2) + kq] = v.w;
    }
    __syncthreads();

    // ---------------- GEMM1: h[b][c] = relu(sum_{d<=r} z[b][d]*W1[r][d][c] + b1[r][c])
    // thread tile: 2 batches (rg) x 16 cols (cg). W1 streamed from global (L2-hot).
    const int rg = tid & 15;            // batches 2rg, 2rg+1
    const int cg = tid >> 4;            // cols 16cg..16cg+15
    float acc[2][16];
    #pragma unroll
    for (int j = 0; j < 2; ++j)
        #pragma unroll
        for (int i = 0; i < 16; ++i) acc[j][i] = 0.0f;

    const float* w1p = W1 + (r * D_TOT) * H_TOT + (cg << 4);
    #pragma unroll 4
    for (int d = 0; d <= r; ++d) {
        float2 zv = *reinterpret_cast<const float2*>(&z_t[d * TB + (rg << 1)]);
        const float* wrow = w1p + d * H_TOT;
        float wv[16];
        *reinterpret_cast<float4*>(&wv[0])  = *reinterpret_cast<const float4*>(wrow + 0);
        *reinterpret_cast<float4*>(&wv[4])  = *reinterpret_cast<const float4*>(wrow + 4);
        *reinterpret_cast<float4*>(&wv[8])  = *reinterpret_cast<const float4*>(wrow + 8);
        *reinterpret_cast<float4*>(&wv[12]) = *reinterpret_cast<const float4*>(wrow + 12);
        #pragma unroll
        for (int i = 0; i < 16; ++i) {
            acc[0][i] = fmaf(zv.x, wv[i], acc[0][i]);
            acc[1][i] = fmaf(zv.y, wv[i], acc[1][i]);
        }
    }

    // bias + relu + store h swizzled: value h[b][k] at b*256 + ((k>>2)^((b>>2)&7))*4 + (k&3)
    {
        const int key = (rg >> 1) & 7;  // (b>>2)&7 for b = 2rg+j, j<2
        #pragma unroll
        for (int gi = 0; gi < 4; ++gi) {
            float4 bv = *reinterpret_cast<const float4*>(&b1[r * H_TOT + (cg << 4) + (gi << 2)]);
            #pragma unroll
            for (int j = 0; j < 2; ++j) {
                float4 v;
                v.x = fmaxf(acc[j][4 * gi + 0] + bv.x, 0.0f);
                v.y = fmaxf(acc[j][4 * gi + 1] + bv.y, 0.0f);
                v.z = fmaxf(acc[j][4 * gi + 2] + bv.z, 0.0f);
                v.w = fmaxf(acc[j][4 * gi + 3] + bv.w, 0.0f);
                int bb = (rg << 1) + j;
                int g  = ((cg << 2) + gi) ^ key;
                *reinterpret_cast<float4*>(&h_s[bb * 256 + (g << 2)]) = v;
            }
        }
    }
    __syncthreads();

    // ---------------- GEMM2: raw[b][p] = sum_k h[b][k]*W2[r][k][p]
    // k split across 4 waves (64 k each); lane tile 4b x 3p.
    const int wv_ = tid >> 6;           // wave id: k in [64*wv_, 64*wv_+64)
    const int ln  = tid & 63;
    const int bq  = ln & 7;             // batches 4bq..4bq+3
    const int pg  = ln >> 3;            // p = 3pg..3pg+2
    float acc2[4][3];
    #pragma unroll
    for (int j = 0; j < 4; ++j)
        #pragma unroll
        for (int i = 0; i < 3; ++i) acc2[j][i] = 0.0f;

    #pragma unroll
    for (int c = 0; c < 8; ++c) {
        int k0  = (wv_ << 6) + (c << 3);
        int gk0 = k0 >> 2;              // even
        float w2r[3][8], hr[4][8];
        #pragma unroll
        for (int i = 0; i < 3; ++i) {
            int p = 3 * pg + i, pk = p & 7;
            *reinterpret_cast<float4*>(&w2r[i][0]) =
                *reinterpret_cast<const float4*>(&w2t[p * 256 + (((gk0 + 0) ^ pk) << 2)]);
            *reinterpret_cast<float4*>(&w2r[i][4]) =
                *reinterpret_cast<const float4*>(&w2t[p * 256 + (((gk0 + 1) ^ pk) << 2)]);
        }
        #pragma unroll
        for (int j = 0; j < 4; ++j) {
            int bb = 4 * bq + j;        // (bb>>2)&7 == bq
            *reinterpret_cast<float4*>(&hr[j][0]) =
                *reinterpret_cast<const float4*>(&h_s[bb * 256 + (((gk0 + 0) ^ bq) << 2)]);
            *reinterpret_cast<float4*>(&hr[j][4]) =
                *reinterpret_cast<const float4*>(&h_s[bb * 256 + (((gk0 + 1) ^ bq) << 2)]);
        }
        #pragma unroll
        for (int kk = 0; kk < 8; ++kk)
            #pragma unroll
            for (int j = 0; j < 4; ++j)
                #pragma unroll
                for (int i = 0; i < 3; ++i)
                    acc2[j][i] = fmaf(hr[j][kk], w2r[i][kk], acc2[j][i]);
    }
    __syncthreads();                    // all w2t reads done before aliasing as `part`
    #pragma unroll
    for (int j = 0; j < 4; ++j)
        #pragma unroll
        for (int i = 0; i < 3; ++i)
            part[((wv_ << 5) + 4 * bq + j) * PK_TOT + 3 * pg + i] = acc2[j][i];
    __syncthreads();

    // ---------------- reduce partials + flow epilogue ----------------
    // thread = (batch eb, mixture k = ej). triplet p = {ej, 8+ej, 16+ej}.
    {
        const int eb = tid >> 3;        // 0..31
        const int ej = tid & 7;         // 0..7
        float rawa = b2[r * PK_TOT + ej];
        float rawb = b2[r * PK_TOT + 8 + ej];
        float rawr = b2[r * PK_TOT + 16 + ej];
        #pragma unroll
        for (int w = 0; w < 4; ++w) {
            rawa += part[((w << 5) + eb) * PK_TOT + ej];
            rawb += part[((w << 5) + eb) * PK_TOT + 8 + ej];
            rawr += part[((w << 5) + eb) * PK_TOT + 16 + ej];
        }
        float zi = z_t[(r + 1) * TB + eb];
        float t  = tanf((zi - PI_F) * 0.5f);
        float al = expf(rawa);
        float g  = fmaf(al, t, rawb);
        float X  = 2.0f * atanf(g) + PI_F;
        float dv = al * (1.0f + t * t) / (1.0f + g * g);

        float m = rawr;
        m = fmaxf(m, __shfl_xor(m, 1));
        m = fmaxf(m, __shfl_xor(m, 2));
        m = fmaxf(m, __shfl_xor(m, 4));
        float e  = expf(rawr - m);
        float se = e, sx = e * X, sd = e * dv;
        se += __shfl_xor(se, 1); se += __shfl_xor(se, 2); se += __shfl_xor(se, 4);
        sx += __shfl_xor(sx, 1); sx += __shfl_xor(sx, 2); sx += __shfl_xor(sx, 4);
        sd += __shfl_xor(sd, 1); sd += __shfl_xor(sd, 2); sd += __shfl_xor(sd, 4);

        if (ej == 0) {
            int gb = b0 + eb;
            out[gb * D_TOT + (r + 1)] = sx / se;                       // x[b][r+1]
            atomicAdd(&out[B_TOT * D_TOT + gb], logf(sd / se));        // log_det[b]
        }
    }
}

extern "C" void kernel_launch(void* const* d_in, const int* in_sizes, int n_in,
                              void* d_out, int out_size, void* d_ws, size_t ws_size,
                              hipStream_t stream) {
    const float* z  = (const float*)d_in[0];
    const float* W1 = (const float*)d_in[1];
    const float* b1 = (const float*)d_in[2];
    const float* W2 = (const float*)d_in[3];
    const float* b2 = (const float*)d_in[4];
    float* out = (float*)d_out;

    init_out_kernel<<<dim3((B_TOT + 255) / 256), dim3(256), 0, stream>>>(out);
    flow_main<<<dim3(B_TOT / TB, R_TOT), dim3(256), 0, stream>>>(z, W1, b1, W2, b2, out);
}

// Round 2
// 228.758 us; speedup vs baseline: 3.0909x; 3.0909x over previous
//
#include <hip/hip_runtime.h>
#include <math.h>

typedef __bf16 bf16x8 __attribute__((ext_vector_type(8)));
typedef float f32x4 __attribute__((ext_vector_type(4)));
typedef unsigned int u32x4 __attribute__((ext_vector_type(4)));

#define B_TOT 16384
#define D_TOT 64
#define R_TOT 63
#define H_TOT 256
#define PK_TOT 24
#define PI_F 3.14159265358979323846f

// ws layout: W1F fragments then W2F fragments (u32 units)
#define W2F_BASE_U32 1032192u
#define WS_NEED 6193152u

#define MFMA16(a, b, c) __builtin_amdgcn_mfma_f32_16x16x32_bf16((a), (b), (c), 0, 0, 0)

__device__ __forceinline__ unsigned short bf16_rtne(float f) {
    unsigned u = __float_as_uint(f);
    unsigned rr = u + 0x7FFFu + ((u >> 16) & 1u);
    return (unsigned short)(rr >> 16);
}

__global__ void init_out_kernel(float* __restrict__ out) {
    int b = blockIdx.x * 256 + threadIdx.x;
    if (b < B_TOT) {
        out[(size_t)b * D_TOT] = 0.0f;            // x[:,0] = 0
        out[(size_t)B_TOT * D_TOT + b] = 0.0f;    // log_det = 0
    }
}

// ---------------- prep: weights -> split-bf16 MFMA fragments in ws ----------------
// W1F: frag = ((r*16+nt)*2+t)*2+plane ; lane granule of 8 bf16:
//   n = nt*16 + (lane&15), d = t*32 + (lane>>4)*8 + j, masked d<=r (K padded to 64)
// W2F: frag = ((r*2+nt)*8+ks)*2+plane ; n = nt*16+(lane&15) (0 if n>=24), k = ks*32+(lane>>4)*8+j
__global__ void prep_weights(const float* __restrict__ W1,
                             const float* __restrict__ W2,
                             unsigned int* __restrict__ wsf)
{
    int gid = blockIdx.x * 256 + threadIdx.x;
    if (gid >= 193536) return;
    float v[8];
    unsigned int* dst;
    if (gid < 129024) {
        int lane = gid & 63;
        int q = gid >> 6;
        int t = q & 1; q >>= 1;
        int nt = q & 15; int r = q >> 4;
        int n  = (nt << 4) + (lane & 15);
        int kb = (t << 5) + ((lane >> 4) << 3);
        #pragma unroll
        for (int j = 0; j < 8; ++j) {
            int d = kb + j;
            v[j] = (d <= r) ? W1[(size_t)(r * 64 + d) * 256 + n] : 0.0f;
        }
        int frag = ((r * 16 + nt) * 2 + t) * 2;
        dst = wsf + ((size_t)frag * 64 + lane) * 4;
    } else {
        int g2 = gid - 129024;
        int lane = g2 & 63;
        int q = g2 >> 6;
        int ks = q & 7; q >>= 3;
        int nt = q & 1; int r = q >> 1;
        int n  = (nt << 4) + (lane & 15);
        int kb = (ks << 5) + ((lane >> 4) << 3);
        #pragma unroll
        for (int j = 0; j < 8; ++j) {
            int k = kb + j;
            v[j] = (n < PK_TOT) ? W2[(size_t)(r * 256 + k) * PK_TOT + n] : 0.0f;
        }
        int frag = ((r * 2 + nt) * 8 + ks) * 2;
        dst = wsf + W2F_BASE_U32 + ((size_t)frag * 64 + lane) * 4;
    }
    unsigned hw[4], lw[4];
    #pragma unroll
    for (int i = 0; i < 4; ++i) {
        float a = v[2 * i], b = v[2 * i + 1];
        unsigned ua = __float_as_uint(a), ub = __float_as_uint(b);
        float ra = a - __uint_as_float(ua & 0xFFFF0000u);
        float rb = b - __uint_as_float(ub & 0xFFFF0000u);
        hw[i] = (ua >> 16) | (ub & 0xFFFF0000u);
        lw[i] = (unsigned)bf16_rtne(ra) | ((unsigned)bf16_rtne(rb) << 16);
    }
    *reinterpret_cast<u32x4*>(dst)       = u32x4{hw[0], hw[1], hw[2], hw[3]};
    *reinterpret_cast<u32x4*>(dst + 256) = u32x4{lw[0], lw[1], lw[2], lw[3]};
}

// ---------------- main MFMA kernel: block = 64 batches x one r, 4 waves ----------------
// LDS 48KB: [0,16K) z split planes (later: partials [2][64][32]f32),
//           [16K,32K) h_hi half-tile [64][128]bf16, [32K,48K) h_lo.
// All LDS tiles granule(16B)-XOR-swizzled by (row&7).
__global__ __launch_bounds__(256, 2) void flow_mfma(
    const float* __restrict__ z, const unsigned int* __restrict__ wsf,
    const float* __restrict__ b1, const float* __restrict__ b2,
    float* __restrict__ out)
{
    const int r   = blockIdx.y;
    const int b0  = blockIdx.x << 6;
    const int tid = threadIdx.x;
    const int w   = tid >> 6;
    const int l   = tid & 63;
    const int l15 = l & 15, l4 = l >> 4, key = l & 7;

    __shared__ __align__(16) unsigned char sm[49152];

    // ---- stage z split (hi trunc / lo rtne) ----
    {
        const int m  = tid >> 2;
        const int dq = (tid & 3) << 4;
        const float* zp = z + (size_t)(b0 + m) * 64 + dq;
        const int mkey = m & 7;
        #pragma unroll
        for (int qq = 0; qq < 4; ++qq) {
            float4 val = *reinterpret_cast<const float4*>(zp + (qq << 2));
            int d0 = dq + (qq << 2);
            float vv[4] = {val.x, val.y, val.z, val.w};
            unsigned short h[4], lo[4];
            #pragma unroll
            for (int i = 0; i < 4; ++i) {
                unsigned u = __float_as_uint(vv[i]);
                h[i]  = (unsigned short)(u >> 16);
                lo[i] = bf16_rtne(vv[i] - __uint_as_float(u & 0xFFFF0000u));
            }
            int off = (m << 7) + ((((d0 >> 3)) ^ mkey) << 4) + (((d0 >> 2) & 1) << 3);
            *reinterpret_cast<uint2*>(sm + off) =
                make_uint2(h[0] | ((unsigned)h[1] << 16), h[2] | ((unsigned)h[3] << 16));
            *reinterpret_cast<uint2*>(sm + 8192 + off) =
                make_uint2(lo[0] | ((unsigned)lo[1] << 16), lo[2] | ((unsigned)lo[3] << 16));
        }
    }
    __syncthreads();

    // ---- GEMM1 (output-transposed): D1[n][m] = sum_d W1m[d][n] * z[m][d] ----
    bf16x8 zf[4][2][2];   // [mt][t][plane] B-operand fragments (batch = l&15)
    #pragma unroll
    for (int mt = 0; mt < 4; ++mt)
        #pragma unroll
        for (int t = 0; t < 2; ++t) {
            int m = (mt << 4) + l15;
            int off = (m << 7) + ((((t << 2) + l4) ^ key) << 4);
            zf[mt][t][0] = __builtin_bit_cast(bf16x8, *reinterpret_cast<u32x4*>(sm + off));
            zf[mt][t][1] = __builtin_bit_cast(bf16x8, *reinterpret_cast<u32x4*>(sm + 8192 + off));
        }

    f32x4 acc1[4][4];     // [ntl][mt]
    #pragma unroll
    for (int a = 0; a < 4; ++a)
        #pragma unroll
        for (int b = 0; b < 4; ++b) acc1[a][b] = f32x4{0.f, 0.f, 0.f, 0.f};

    #pragma unroll
    for (int ntl = 0; ntl < 4; ++ntl) {
        const int nt = (w << 2) + ntl;
        bf16x8 af[2][2];  // [t][plane] A-operand (W1^T) fragments from ws
        #pragma unroll
        for (int t = 0; t < 2; ++t)
            #pragma unroll
            for (int pl = 0; pl < 2; ++pl) {
                unsigned fi = (((unsigned)(r * 16 + nt) * 2 + t) * 2 + pl);
                af[t][pl] = __builtin_bit_cast(bf16x8,
                    *reinterpret_cast<const u32x4*>(wsf + (size_t)fi * 256 + (l << 2)));
            }
        #pragma unroll
        for (int t = 0; t < 2; ++t) {
            #pragma unroll
            for (int mt = 0; mt < 4; ++mt)
                acc1[ntl][mt] = MFMA16(af[t][0], zf[mt][t][0], acc1[ntl][mt]);
            #pragma unroll
            for (int mt = 0; mt < 4; ++mt)
                acc1[ntl][mt] = MFMA16(af[t][0], zf[mt][t][1], acc1[ntl][mt]);
            #pragma unroll
            for (int mt = 0; mt < 4; ++mt)
                acc1[ntl][mt] = MFMA16(af[t][1], zf[mt][t][0], acc1[ntl][mt]);
        }
    }

    // bias + relu + split-bf16, write this wave's 64 h-columns into the half-tile
    auto write_h = [&]() {
        #pragma unroll
        for (int ntl = 0; ntl < 4; ++ntl) {
            float4 bv = *reinterpret_cast<const float4*>(
                b1 + (size_t)r * 256 + (w << 6) + (ntl << 4) + (l4 << 2));
            float bvv[4] = {bv.x, bv.y, bv.z, bv.w};
            #pragma unroll
            for (int mt = 0; mt < 4; ++mt) {
                unsigned short h[4], lo[4];
                #pragma unroll
                for (int i = 0; i < 4; ++i) {
                    float vv = fmaxf(acc1[ntl][mt][i] + bvv[i], 0.0f);
                    unsigned u = __float_as_uint(vv);
                    h[i]  = (unsigned short)(u >> 16);
                    lo[i] = bf16_rtne(vv - __uint_as_float(u & 0xFFFF0000u));
                }
                int m   = (mt << 4) + l15;
                int gl  = ((w & 1) << 3) + (ntl << 1) + (l4 >> 1);
                int off = (m << 8) + ((gl ^ key) << 4) + ((l4 & 1) << 3);
                *reinterpret_cast<uint2*>(sm + 16384 + off) =
                    make_uint2(h[0] | ((unsigned)h[1] << 16), h[2] | ((unsigned)h[3] << 16));
                *reinterpret_cast<uint2*>(sm + 32768 + off) =
                    make_uint2(lo[0] | ((unsigned)lo[1] << 16), lo[2] | ((unsigned)lo[3] << 16));
            }
        }
    };

    f32x4 acc2[2][4];     // [nt2][mt]  D2[n][m] = sum_k W2[k][n] h[m][k]
    #pragma unroll
    for (int a = 0; a < 2; ++a)
        #pragma unroll
        for (int b = 0; b < 4; ++b) acc2[a][b] = f32x4{0.f, 0.f, 0.f, 0.f};

    auto gemm2 = [&](int p) {
        const int ks = (p << 2) + w;   // wave's global k-step (32 k each)
        bf16x8 wf[2][2];
        #pragma unroll
        for (int nt2 = 0; nt2 < 2; ++nt2)
            #pragma unroll
            for (int pl = 0; pl < 2; ++pl) {
                unsigned fi = (((unsigned)(r * 2 + nt2) * 8 + ks) * 2 + pl);
                wf[nt2][pl] = __builtin_bit_cast(bf16x8,
                    *reinterpret_cast<const u32x4*>(wsf + W2F_BASE_U32 + (size_t)fi * 256 + (l << 2)));
            }
        bf16x8 hfr[4][2];
        #pragma unroll
        for (int mt = 0; mt < 4; ++mt) {
            int m   = (mt << 4) + l15;
            int off = (m << 8) + ((((w << 2) + l4) ^ key) << 4);
            hfr[mt][0] = __builtin_bit_cast(bf16x8, *reinterpret_cast<u32x4*>(sm + 16384 + off));
            hfr[mt][1] = __builtin_bit_cast(bf16x8, *reinterpret_cast<u32x4*>(sm + 32768 + off));
        }
        #pragma unroll
        for (int nt2 = 0; nt2 < 2; ++nt2)
            #pragma unroll
            for (int mt = 0; mt < 4; ++mt)
                acc2[nt2][mt] = MFMA16(wf[nt2][0], hfr[mt][0], acc2[nt2][mt]);
        #pragma unroll
        for (int nt2 = 0; nt2 < 2; ++nt2)
            #pragma unroll
            for (int mt = 0; mt < 4; ++mt)
                acc2[nt2][mt] = MFMA16(wf[nt2][0], hfr[mt][1], acc2[nt2][mt]);
        #pragma unroll
        for (int nt2 = 0; nt2 < 2; ++nt2)
            #pragma unroll
            for (int mt = 0; mt < 4; ++mt)
                acc2[nt2][mt] = MFMA16(wf[nt2][1], hfr[mt][0], acc2[nt2][mt]);
    };

    if (w < 2) write_h();       // waves 0,1 own h-cols 0..127
    __syncthreads();
    gemm2(0);                   // k = 0..127
    __syncthreads();
    if (w >= 2) write_h();      // h-cols 128..255 overwrite the half-tile
    __syncthreads();
    gemm2(1);                   // k = 128..255

    // ---- cross-wave reduce of raw via LDS (aliases dead z region) ----
    auto part_off = [&](int ph, int nt2, int mt) -> int {
        int m = (mt << 4) + l15;
        return (((ph << 6) + m) << 7) + ((((nt2 << 2) + l4) ^ key) << 4);
    };
    if (w < 2) {
        #pragma unroll
        for (int nt2 = 0; nt2 < 2; ++nt2)
            #pragma unroll
            for (int mt = 0; mt < 4; ++mt)
                *reinterpret_cast<f32x4*>(sm + part_off(w, nt2, mt)) = acc2[nt2][mt];
    }
    __syncthreads();
    if (w >= 2) {
        #pragma unroll
        for (int nt2 = 0; nt2 < 2; ++nt2)
            #pragma unroll
            for (int mt = 0; mt < 4; ++mt) {
                f32x4* p = reinterpret_cast<f32x4*>(sm + part_off(w - 2, nt2, mt));
                *p = *p + acc2[nt2][mt];
            }
    }
    __syncthreads();

    // ---- flow epilogue (same math as verified fp32 round) ----
    #pragma unroll
    for (int mh = 0; mh < 2; ++mh) {
        const int m  = (mh << 5) + (tid >> 3);
        const int j  = tid & 7;
        const int mk = m & 7;
        float ra = b2[(size_t)r * 24 + j];
        float rb = b2[(size_t)r * 24 + 8 + j];
        float rr = b2[(size_t)r * 24 + 16 + j];
        #pragma unroll
        for (int ph = 0; ph < 2; ++ph) {
            const int base = (((ph << 6) + m) << 7);
            const int sub  = (j & 3) << 2;
            ra += *reinterpret_cast<float*>(sm + base + ((((j) >> 2) ^ mk) << 4) + sub);
            rb += *reinterpret_cast<float*>(sm + base + ((((8 + j) >> 2) ^ mk) << 4) + sub);
            rr += *reinterpret_cast<float*>(sm + base + ((((16 + j) >> 2) ^ mk) << 4) + sub);
        }
        float zi = z[(size_t)(b0 + m) * 64 + r + 1];
        float t  = tanf((zi - PI_F) * 0.5f);
        float al = expf(ra);
        float g  = fmaf(al, t, rb);
        float X  = 2.0f * atanf(g) + PI_F;
        float dv = al * (1.0f + t * t) / (1.0f + g * g);
        float mx = rr;
        mx = fmaxf(mx, __shfl_xor(mx, 1));
        mx = fmaxf(mx, __shfl_xor(mx, 2));
        mx = fmaxf(mx, __shfl_xor(mx, 4));
        float e = expf(rr - mx);
        float se = e, sx = e * X, sd = e * dv;
        se += __shfl_xor(se, 1); se += __shfl_xor(se, 2); se += __shfl_xor(se, 4);
        sx += __shfl_xor(sx, 1); sx += __shfl_xor(sx, 2); sx += __shfl_xor(sx, 4);
        sd += __shfl_xor(sd, 1); sd += __shfl_xor(sd, 2); sd += __shfl_xor(sd, 4);
        if (j == 0) {
            int gb = b0 + m;
            out[(size_t)gb * D_TOT + r + 1] = sx / se;
            atomicAdd(&out[(size_t)B_TOT * D_TOT + gb], logf(sd / se));
        }
    }
}

// ---------------- fp32 fallback (round-1 kernel, known-correct) ----------------
__global__ __launch_bounds__(256, 2) void flow_fp32(
    const float* __restrict__ z,  const float* __restrict__ W1,
    const float* __restrict__ b1, const float* __restrict__ W2,
    const float* __restrict__ b2, float* __restrict__ out)
{
    const int r   = blockIdx.y;
    const int b0  = blockIdx.x * 32;
    const int tid = threadIdx.x;

    __shared__ float smem[16384];
    float* z_t  = smem;
    float* h_s  = smem + 2048;
    float* w2t  = smem + 2048 + 8192;
    float* part = w2t;

    #pragma unroll
    for (int it = 0; it < 2; ++it) {
        int idx4 = it * 256 + tid;
        int brow = idx4 >> 4;
        int dq   = (idx4 & 15) << 2;
        float4 v = *reinterpret_cast<const float4*>(&z[(size_t)(b0 + brow) * D_TOT + dq]);
        z_t[(dq + 0) * 32 + brow] = v.x;
        z_t[(dq + 1) * 32 + brow] = v.y;
        z_t[(dq + 2) * 32 + brow] = v.z;
        z_t[(dq + 3) * 32 + brow] = v.w;
    }
    #pragma unroll
    for (int it = 0; it < 6; ++it) {
        int idx4 = it * 256 + tid;
        int k  = idx4 / 6;
        int pq = (idx4 - k * 6) << 2;
        float4 v = *reinterpret_cast<const float4*>(&W2[(size_t)(r * H_TOT + k) * PK_TOT + pq]);
        int gk = k >> 2, kq = k & 3;
        w2t[(pq + 0) * 256 + (((gk) ^ ((pq + 0) & 7)) << 2) + kq] = v.x;
        w2t[(pq + 1) * 256 + (((gk) ^ ((pq + 1) & 7)) << 2) + kq] = v.y;
        w2t[(pq + 2) * 256 + (((gk) ^ ((pq + 2) & 7)) << 2) + kq] = v.z;
        w2t[(pq + 3) * 256 + (((gk) ^ ((pq + 3) & 7)) << 2) + kq] = v.w;
    }
    __syncthreads();

    const int rg = tid & 15;
    const int cg = tid >> 4;
    float acc[2][16];
    #pragma unroll
    for (int j = 0; j < 2; ++j)
        #pragma unroll
        for (int i = 0; i < 16; ++i) acc[j][i] = 0.0f;

    const float* w1p = W1 + (size_t)(r * D_TOT) * H_TOT + (cg << 4);
    #pragma unroll 4
    for (int d = 0; d <= r; ++d) {
        float2 zv = *reinterpret_cast<const float2*>(&z_t[d * 32 + (rg << 1)]);
        const float* wrow = w1p + (size_t)d * H_TOT;
        float wv[16];
        *reinterpret_cast<float4*>(&wv[0])  = *reinterpret_cast<const float4*>(wrow + 0);
        *reinterpret_cast<float4*>(&wv[4])  = *reinterpret_cast<const float4*>(wrow + 4);
        *reinterpret_cast<float4*>(&wv[8])  = *reinterpret_cast<const float4*>(wrow + 8);
        *reinterpret_cast<float4*>(&wv[12]) = *reinterpret_cast<const float4*>(wrow + 12);
        #pragma unroll
        for (int i = 0; i < 16; ++i) {
            acc[0][i] = fmaf(zv.x, wv[i], acc[0][i]);
            acc[1][i] = fmaf(zv.y, wv[i], acc[1][i]);
        }
    }
    {
        const int key = (rg >> 1) & 7;
        #pragma unroll
        for (int gi = 0; gi < 4; ++gi) {
            float4 bv = *reinterpret_cast<const float4*>(&b1[(size_t)r * H_TOT + (cg << 4) + (gi << 2)]);
            #pragma unroll
            for (int j = 0; j < 2; ++j) {
                float4 v;
                v.x = fmaxf(acc[j][4 * gi + 0] + bv.x, 0.0f);
                v.y = fmaxf(acc[j][4 * gi + 1] + bv.y, 0.0f);
                v.z = fmaxf(acc[j][4 * gi + 2] + bv.z, 0.0f);
                v.w = fmaxf(acc[j][4 * gi + 3] + bv.w, 0.0f);
                int bb = (rg << 1) + j;
                int g  = ((cg << 2) + gi) ^ key;
                *reinterpret_cast<float4*>(&h_s[bb * 256 + (g << 2)]) = v;
            }
        }
    }
    __syncthreads();

    const int wv_ = tid >> 6;
    const int ln  = tid & 63;
    const int bq  = ln & 7;
    const int pg  = ln >> 3;
    float acc2[4][3];
    #pragma unroll
    for (int j = 0; j < 4; ++j)
        #pragma unroll
        for (int i = 0; i < 3; ++i) acc2[j][i] = 0.0f;

    #pragma unroll
    for (int c = 0; c < 8; ++c) {
        int k0  = (wv_ << 6) + (c << 3);
        int gk0 = k0 >> 2;
        float w2r[3][8], hr[4][8];
        #pragma unroll
        for (int i = 0; i < 3; ++i) {
            int p = 3 * pg + i, pk = p & 7;
            *reinterpret_cast<float4*>(&w2r[i][0]) =
                *reinterpret_cast<const float4*>(&w2t[p * 256 + (((gk0 + 0) ^ pk) << 2)]);
            *reinterpret_cast<float4*>(&w2r[i][4]) =
                *reinterpret_cast<const float4*>(&w2t[p * 256 + (((gk0 + 1) ^ pk) << 2)]);
        }
        #pragma unroll
        for (int j = 0; j < 4; ++j) {
            int bb = 4 * bq + j;
            *reinterpret_cast<float4*>(&hr[j][0]) =
                *reinterpret_cast<const float4*>(&h_s[bb * 256 + (((gk0 + 0) ^ bq) << 2)]);
            *reinterpret_cast<float4*>(&hr[j][4]) =
                *reinterpret_cast<const float4*>(&h_s[bb * 256 + (((gk0 + 1) ^ bq) << 2)]);
        }
        #pragma unroll
        for (int kk = 0; kk < 8; ++kk)
            #pragma unroll
            for (int j = 0; j < 4; ++j)
                #pragma unroll
                for (int i = 0; i < 3; ++i)
                    acc2[j][i] = fmaf(hr[j][kk], w2r[i][kk], acc2[j][i]);
    }
    __syncthreads();
    #pragma unroll
    for (int j = 0; j < 4; ++j)
        #pragma unroll
        for (int i = 0; i < 3; ++i)
            part[((wv_ << 5) + 4 * bq + j) * PK_TOT + 3 * pg + i] = acc2[j][i];
    __syncthreads();

    {
        const int eb = tid >> 3;
        const int ej = tid & 7;
        float rawa = b2[(size_t)r * PK_TOT + ej];
        float rawb = b2[(size_t)r * PK_TOT + 8 + ej];
        float rawr = b2[(size_t)r * PK_TOT + 16 + ej];
        #pragma unroll
        for (int w = 0; w < 4; ++w) {
            rawa += part[((w << 5) + eb) * PK_TOT + ej];
            rawb += part[((w << 5) + eb) * PK_TOT + 8 + ej];
            rawr += part[((w << 5) + eb) * PK_TOT + 16 + ej];
        }
        float zi = z_t[(r + 1) * 32 + eb];
        float t  = tanf((zi - PI_F) * 0.5f);
        float al = expf(rawa);
        float g  = fmaf(al, t, rawb);
        float X  = 2.0f * atanf(g) + PI_F;
        float dv = al * (1.0f + t * t) / (1.0f + g * g);
        float m = rawr;
        m = fmaxf(m, __shfl_xor(m, 1));
        m = fmaxf(m, __shfl_xor(m, 2));
        m = fmaxf(m, __shfl_xor(m, 4));
        float e  = expf(rawr - m);
        float se = e, sx = e * X, sd = e * dv;
        se += __shfl_xor(se, 1); se += __shfl_xor(se, 2); se += __shfl_xor(se, 4);
        sx += __shfl_xor(sx, 1); sx += __shfl_xor(sx, 2); sx += __shfl_xor(sx, 4);
        sd += __shfl_xor(sd, 1); sd += __shfl_xor(sd, 2); sd += __shfl_xor(sd, 4);
        if (ej == 0) {
            int gb = b0 + eb;
            out[(size_t)gb * D_TOT + (r + 1)] = sx / se;
            atomicAdd(&out[(size_t)B_TOT * D_TOT + gb], logf(sd / se));
        }
    }
}

extern "C" void kernel_launch(void* const* d_in, const int* in_sizes, int n_in,
                              void* d_out, int out_size, void* d_ws, size_t ws_size,
                              hipStream_t stream) {
    const float* z  = (const float*)d_in[0];
    const float* W1 = (const float*)d_in[1];
    const float* b1 = (const float*)d_in[2];
    const float* W2 = (const float*)d_in[3];
    const float* b2 = (const float*)d_in[4];
    float* out = (float*)d_out;

    init_out_kernel<<<dim3(B_TOT / 256), dim3(256), 0, stream>>>(out);
    if (ws_size >= (size_t)WS_NEED) {
        prep_weights<<<dim3(756), dim3(256), 0, stream>>>(W1, W2, (unsigned int*)d_ws);
        flow_mfma<<<dim3(B_TOT / 64, R_TOT), dim3(256), 0, stream>>>(
            z, (const unsigned int*)d_ws, b1, b2, out);
    } else {
        flow_fp32<<<dim3(B_TOT / 32, R_TOT), dim3(256), 0, stream>>>(z, W1, b1, W2, b2, out);
    }
}

// Round 3
// 193.884 us; speedup vs baseline: 3.6469x; 1.1799x over previous
//
#include <hip/hip_runtime.h>
#include <math.h>
#include <type_traits>

typedef __bf16 bf16x8 __attribute__((ext_vector_type(8)));
typedef float f32x4 __attribute__((ext_vector_type(4)));
typedef unsigned int u32x4 __attribute__((ext_vector_type(4)));

#define B_TOT 16384
#define D_TOT 64
#define R_TOT 63
#define H_TOT 256
#define PK_TOT 24
#define PI_F 3.14159265358979323846f

// ws layout: W1F fragments then W2F fragments (u32 units)
#define W2F_BASE_U32 1032192u
#define WS_NEED 6193152u

#define MFMA16(a, b, c) __builtin_amdgcn_mfma_f32_16x16x32_bf16((a), (b), (c), 0, 0, 0)

__device__ __forceinline__ unsigned short bf16_rtne(float f) {
    unsigned u = __float_as_uint(f);
    unsigned rr = u + 0x7FFFu + ((u >> 16) & 1u);
    return (unsigned short)(rr >> 16);
}

// one v_cvt_pk_bf16_f32: packs rtne(a) | rtne(b)<<16 (no builtin on gfx950)
__device__ __forceinline__ unsigned cvt_pk_bf16(float a, float b) {
    unsigned r;
    asm("v_cvt_pk_bf16_f32 %0, %1, %2" : "=v"(r) : "v"(a), "v"(b));
    return r;
}

// split 4 f32 -> hi plane (truncated bf16 x4) + lo plane (rtne residual x4)
__device__ __forceinline__ void split4(const float* v, uint2& hi, uint2& lo) {
    unsigned u0 = __float_as_uint(v[0]), u1 = __float_as_uint(v[1]);
    unsigned u2 = __float_as_uint(v[2]), u3 = __float_as_uint(v[3]);
    hi.x = __builtin_amdgcn_perm(u1, u0, 0x07060302u);   // {u1.hi16, u0.hi16}
    hi.y = __builtin_amdgcn_perm(u3, u2, 0x07060302u);
    float r0 = v[0] - __uint_as_float(u0 & 0xFFFF0000u);
    float r1 = v[1] - __uint_as_float(u1 & 0xFFFF0000u);
    float r2 = v[2] - __uint_as_float(u2 & 0xFFFF0000u);
    float r3 = v[3] - __uint_as_float(u3 & 0xFFFF0000u);
    lo.x = cvt_pk_bf16(r0, r1);
    lo.y = cvt_pk_bf16(r2, r3);
}

__global__ void init_out_kernel(float* __restrict__ out) {
    int b = blockIdx.x * 256 + threadIdx.x;
    if (b < B_TOT) {
        out[(size_t)b * D_TOT] = 0.0f;            // x[:,0] = 0
        out[(size_t)B_TOT * D_TOT + b] = 0.0f;    // log_det = 0
    }
}

// ---------------- prep: weights -> split-bf16 MFMA fragments in ws ----------------
__global__ void prep_weights(const float* __restrict__ W1,
                             const float* __restrict__ W2,
                             unsigned int* __restrict__ wsf)
{
    int gid = blockIdx.x * 256 + threadIdx.x;
    if (gid >= 193536) return;
    float v[8];
    unsigned int* dst;
    if (gid < 129024) {
        int lane = gid & 63;
        int q = gid >> 6;
        int t = q & 1; q >>= 1;
        int nt = q & 15; int r = q >> 4;
        int n  = (nt << 4) + (lane & 15);
        int kb = (t << 5) + ((lane >> 4) << 3);
        #pragma unroll
        for (int j = 0; j < 8; ++j) {
            int d = kb + j;
            v[j] = (d <= r) ? W1[(size_t)(r * 64 + d) * 256 + n] : 0.0f;
        }
        int frag = ((r * 16 + nt) * 2 + t) * 2;
        dst = wsf + ((size_t)frag * 64 + lane) * 4;
    } else {
        int g2 = gid - 129024;
        int lane = g2 & 63;
        int q = g2 >> 6;
        int ks = q & 7; q >>= 3;
        int nt = q & 1; int r = q >> 1;
        int n  = (nt << 4) + (lane & 15);
        int kb = (ks << 5) + ((lane >> 4) << 3);
        #pragma unroll
        for (int j = 0; j < 8; ++j) {
            int k = kb + j;
            v[j] = (n < PK_TOT) ? W2[(size_t)(r * 256 + k) * PK_TOT + n] : 0.0f;
        }
        int frag = ((r * 2 + nt) * 8 + ks) * 2;
        dst = wsf + W2F_BASE_U32 + ((size_t)frag * 64 + lane) * 4;
    }
    unsigned hw[4], lw[4];
    #pragma unroll
    for (int i = 0; i < 4; ++i) {
        float a = v[2 * i], b = v[2 * i + 1];
        unsigned ua = __float_as_uint(a), ub = __float_as_uint(b);
        float ra = a - __uint_as_float(ua & 0xFFFF0000u);
        float rb = b - __uint_as_float(ub & 0xFFFF0000u);
        hw[i] = (ua >> 16) | (ub & 0xFFFF0000u);
        lw[i] = (unsigned)bf16_rtne(ra) | ((unsigned)bf16_rtne(rb) << 16);
    }
    *reinterpret_cast<u32x4*>(dst)       = u32x4{hw[0], hw[1], hw[2], hw[3]};
    *reinterpret_cast<u32x4*>(dst + 256) = u32x4{lw[0], lw[1], lw[2], lw[3]};
}

// ---------------- main MFMA kernel: block = 64 batches x one r, 4 waves ----------------
__global__ __launch_bounds__(256, 2) void flow_mfma(
    const float* __restrict__ z, const unsigned int* __restrict__ wsf,
    const float* __restrict__ b1, const float* __restrict__ b2,
    float* __restrict__ out)
{
    const int r   = blockIdx.y;
    const int b0  = blockIdx.x << 6;
    const int tid = threadIdx.x;
    const int w   = tid >> 6;
    const int l   = tid & 63;
    const int l15 = l & 15, l4 = l >> 4, key = l & 7;

    __shared__ __align__(16) unsigned char sm[49152];

    // ---- stage z split (hi trunc / lo rtne) ----
    {
        const int m  = tid >> 2;
        const int dq = (tid & 3) << 4;
        const float* zp = z + (size_t)(b0 + m) * 64 + dq;
        const int mkey = m & 7;
        #pragma unroll
        for (int qq = 0; qq < 4; ++qq) {
            float4 val = *reinterpret_cast<const float4*>(zp + (qq << 2));
            int d0 = dq + (qq << 2);
            float vv[4] = {val.x, val.y, val.z, val.w};
            uint2 hi, lo;
            split4(vv, hi, lo);
            int off = (m << 7) + ((((d0 >> 3)) ^ mkey) << 4) + (((d0 >> 2) & 1) << 3);
            *reinterpret_cast<uint2*>(sm + off) = hi;
            *reinterpret_cast<uint2*>(sm + 8192 + off) = lo;
        }
    }
    __syncthreads();

    // ---- GEMM1 (output-transposed): D1[n][m] = sum_d W1m[d][n] * z[m][d] ----
    f32x4 acc1[4][4];     // [ntl][mt]
    #pragma unroll
    for (int a = 0; a < 4; ++a)
        #pragma unroll
        for (int b = 0; b < 4; ++b) acc1[a][b] = f32x4{0.f, 0.f, 0.f, 0.f};

    auto run_gemm1 = [&](auto FULLC) {
        constexpr bool FULL = decltype(FULLC)::value;
        constexpr int NT = FULL ? 2 : 1;
        bf16x8 zf[4][NT][2];   // [mt][t][plane]
        #pragma unroll
        for (int mt = 0; mt < 4; ++mt)
            #pragma unroll
            for (int t = 0; t < NT; ++t) {
                int m = (mt << 4) + l15;
                int off = (m << 7) + ((((t << 2) + l4) ^ key) << 4);
                zf[mt][t][0] = __builtin_bit_cast(bf16x8, *reinterpret_cast<u32x4*>(sm + off));
                zf[mt][t][1] = __builtin_bit_cast(bf16x8, *reinterpret_cast<u32x4*>(sm + 8192 + off));
            }
        const unsigned int* w1b = wsf + (size_t)((r * 16 + (w << 2)) * 4) * 256 + (l << 2);
        #pragma unroll
        for (int ntl = 0; ntl < 4; ++ntl) {
            bf16x8 af[NT][2];
            #pragma unroll
            for (int t = 0; t < NT; ++t)
                #pragma unroll
                for (int pl = 0; pl < 2; ++pl)
                    af[t][pl] = __builtin_bit_cast(bf16x8,
                        *reinterpret_cast<const u32x4*>(w1b + ((ntl * 4 + t * 2 + pl) << 8)));
            #pragma unroll
            for (int t = 0; t < NT; ++t) {
                #pragma unroll
                for (int mt = 0; mt < 4; ++mt)
                    acc1[ntl][mt] = MFMA16(af[t][0], zf[mt][t][0], acc1[ntl][mt]);
                #pragma unroll
                for (int mt = 0; mt < 4; ++mt)
                    acc1[ntl][mt] = MFMA16(af[t][0], zf[mt][t][1], acc1[ntl][mt]);
                #pragma unroll
                for (int mt = 0; mt < 4; ++mt)
                    acc1[ntl][mt] = MFMA16(af[t][1], zf[mt][t][0], acc1[ntl][mt]);
            }
        }
    };
    if (r >= 32) run_gemm1(std::true_type{});
    else         run_gemm1(std::false_type{});

    // bias + relu + split-bf16, write this wave's 64 h-columns into the half-tile
    auto write_h = [&]() {
        #pragma unroll
        for (int ntl = 0; ntl < 4; ++ntl) {
            float4 bv = *reinterpret_cast<const float4*>(
                b1 + (size_t)r * 256 + (w << 6) + (ntl << 4) + (l4 << 2));
            float bvv[4] = {bv.x, bv.y, bv.z, bv.w};
            #pragma unroll
            for (int mt = 0; mt < 4; ++mt) {
                float vv[4];
                #pragma unroll
                for (int i = 0; i < 4; ++i)
                    vv[i] = fmaxf(acc1[ntl][mt][i] + bvv[i], 0.0f);
                uint2 hi, lo;
                split4(vv, hi, lo);
                int m   = (mt << 4) + l15;
                int gl  = ((w & 1) << 3) + (ntl << 1) + (l4 >> 1);
                int off = (m << 8) + ((gl ^ key) << 4) + ((l4 & 1) << 3);
                *reinterpret_cast<uint2*>(sm + 16384 + off) = hi;
                *reinterpret_cast<uint2*>(sm + 32768 + off) = lo;
            }
        }
    };

    f32x4 acc2[2][4];     // [nt2][mt]  D2[n][m] = sum_k W2[k][n] h[m][k]
    #pragma unroll
    for (int a = 0; a < 2; ++a)
        #pragma unroll
        for (int b = 0; b < 4; ++b) acc2[a][b] = f32x4{0.f, 0.f, 0.f, 0.f};

    const unsigned int* w2b = wsf + W2F_BASE_U32 + (size_t)(r * 32) * 256 + (l << 2);
    auto gemm2 = [&](int p) {
        const int ks = (p << 2) + w;   // wave's global k-step (32 k each)
        bf16x8 wf[2][2];
        #pragma unroll
        for (int nt2 = 0; nt2 < 2; ++nt2)
            #pragma unroll
            for (int pl = 0; pl < 2; ++pl)
                wf[nt2][pl] = __builtin_bit_cast(bf16x8,
                    *reinterpret_cast<const u32x4*>(w2b + ((nt2 * 16 + ks * 2 + pl) << 8)));
        bf16x8 hfr[4][2];
        #pragma unroll
        for (int mt = 0; mt < 4; ++mt) {
            int m   = (mt << 4) + l15;
            int off = (m << 8) + ((((w << 2) + l4) ^ key) << 4);
            hfr[mt][0] = __builtin_bit_cast(bf16x8, *reinterpret_cast<u32x4*>(sm + 16384 + off));
            hfr[mt][1] = __builtin_bit_cast(bf16x8, *reinterpret_cast<u32x4*>(sm + 32768 + off));
        }
        #pragma unroll
        for (int nt2 = 0; nt2 < 2; ++nt2)
            #pragma unroll
            for (int mt = 0; mt < 4; ++mt)
                acc2[nt2][mt] = MFMA16(wf[nt2][0], hfr[mt][0], acc2[nt2][mt]);
        #pragma unroll
        for (int nt2 = 0; nt2 < 2; ++nt2)
            #pragma unroll
            for (int mt = 0; mt < 4; ++mt)
                acc2[nt2][mt] = MFMA16(wf[nt2][0], hfr[mt][1], acc2[nt2][mt]);
        #pragma unroll
        for (int nt2 = 0; nt2 < 2; ++nt2)
            #pragma unroll
            for (int mt = 0; mt < 4; ++mt)
                acc2[nt2][mt] = MFMA16(wf[nt2][1], hfr[mt][0], acc2[nt2][mt]);
    };

    if (w < 2) write_h();       // waves 0,1 own h-cols 0..127
    __syncthreads();
    gemm2(0);                   // k = 0..127
    __syncthreads();
    if (w >= 2) write_h();      // h-cols 128..255 overwrite the half-tile
    __syncthreads();
    gemm2(1);                   // k = 128..255

    // ---- cross-wave reduce of raw via LDS (aliases dead z region) ----
    auto part_off = [&](int ph, int nt2, int mt) -> int {
        int m = (mt << 4) + l15;
        return (((ph << 6) + m) << 7) + ((((nt2 << 2) + l4) ^ key) << 4);
    };
    if (w < 2) {
        #pragma unroll
        for (int nt2 = 0; nt2 < 2; ++nt2)
            #pragma unroll
            for (int mt = 0; mt < 4; ++mt)
                *reinterpret_cast<f32x4*>(sm + part_off(w, nt2, mt)) = acc2[nt2][mt];
    }
    __syncthreads();
    if (w >= 2) {
        #pragma unroll
        for (int nt2 = 0; nt2 < 2; ++nt2)
            #pragma unroll
            for (int mt = 0; mt < 4; ++mt) {
                f32x4* p = reinterpret_cast<f32x4*>(sm + part_off(w - 2, nt2, mt));
                *p = *p + acc2[nt2][mt];
            }
    }
    __syncthreads();

    // ---- flow epilogue (fast transcendentals) ----
    #pragma unroll
    for (int mh = 0; mh < 2; ++mh) {
        const int m  = (mh << 5) + (tid >> 3);
        const int j  = tid & 7;
        const int mk = m & 7;
        float ra = b2[(size_t)r * 24 + j];
        float rb = b2[(size_t)r * 24 + 8 + j];
        float rr = b2[(size_t)r * 24 + 16 + j];
        #pragma unroll
        for (int ph = 0; ph < 2; ++ph) {
            const int base = (((ph << 6) + m) << 7);
            const int sub  = (j & 3) << 2;
            ra += *reinterpret_cast<float*>(sm + base + ((((j) >> 2) ^ mk) << 4) + sub);
            rb += *reinterpret_cast<float*>(sm + base + ((((8 + j) >> 2) ^ mk) << 4) + sub);
            rr += *reinterpret_cast<float*>(sm + base + ((((16 + j) >> 2) ^ mk) << 4) + sub);
        }
        float zi = z[(size_t)(b0 + m) * 64 + r + 1];
        // tan((zi - pi)/2) == -cos(zi/2)/sin(zi/2); clamp to avoid inf^2/inf^2 NaN at zi=0
        float s, c;
        __sincosf(zi * 0.5f, &s, &c);
        float t = -c * __builtin_amdgcn_rcpf(s);
        t = fminf(fmaxf(t, -1e8f), 1e8f);
        float al = __expf(ra);
        float g  = fmaf(al, t, rb);
        float X  = 2.0f * atanf(g) + PI_F;
        float dv = al * fmaf(t, t, 1.0f) * __builtin_amdgcn_rcpf(fmaf(g, g, 1.0f));
        float mx = rr;
        mx = fmaxf(mx, __shfl_xor(mx, 1));
        mx = fmaxf(mx, __shfl_xor(mx, 2));
        mx = fmaxf(mx, __shfl_xor(mx, 4));
        float e = __expf(rr - mx);
        float se = e, sx = e * X, sd = e * dv;
        se += __shfl_xor(se, 1); se += __shfl_xor(se, 2); se += __shfl_xor(se, 4);
        sx += __shfl_xor(sx, 1); sx += __shfl_xor(sx, 2); sx += __shfl_xor(sx, 4);
        sd += __shfl_xor(sd, 1); sd += __shfl_xor(sd, 2); sd += __shfl_xor(sd, 4);
        if (j == 0) {
            int gb = b0 + m;
            float rse = __builtin_amdgcn_rcpf(se);
            out[(size_t)gb * D_TOT + r + 1] = sx * rse;
            atomicAdd(&out[(size_t)B_TOT * D_TOT + gb], __logf(sd * rse));
        }
    }
}

// ---------------- fp32 fallback (round-1 kernel, known-correct) ----------------
__global__ __launch_bounds__(256, 2) void flow_fp32(
    const float* __restrict__ z,  const float* __restrict__ W1,
    const float* __restrict__ b1, const float* __restrict__ W2,
    const float* __restrict__ b2, float* __restrict__ out)
{
    const int r   = blockIdx.y;
    const int b0  = blockIdx.x * 32;
    const int tid = threadIdx.x;

    __shared__ float smem[16384];
    float* z_t  = smem;
    float* h_s  = smem + 2048;
    float* w2t  = smem + 2048 + 8192;
    float* part = w2t;

    #pragma unroll
    for (int it = 0; it < 2; ++it) {
        int idx4 = it * 256 + tid;
        int brow = idx4 >> 4;
        int dq   = (idx4 & 15) << 2;
        float4 v = *reinterpret_cast<const float4*>(&z[(size_t)(b0 + brow) * D_TOT + dq]);
        z_t[(dq + 0) * 32 + brow] = v.x;
        z_t[(dq + 1) * 32 + brow] = v.y;
        z_t[(dq + 2) * 32 + brow] = v.z;
        z_t[(dq + 3) * 32 + brow] = v.w;
    }
    #pragma unroll
    for (int it = 0; it < 6; ++it) {
        int idx4 = it * 256 + tid;
        int k  = idx4 / 6;
        int pq = (idx4 - k * 6) << 2;
        float4 v = *reinterpret_cast<const float4*>(&W2[(size_t)(r * H_TOT + k) * PK_TOT + pq]);
        int gk = k >> 2, kq = k & 3;
        w2t[(pq + 0) * 256 + (((gk) ^ ((pq + 0) & 7)) << 2) + kq] = v.x;
        w2t[(pq + 1) * 256 + (((gk) ^ ((pq + 1) & 7)) << 2) + kq] = v.y;
        w2t[(pq + 2) * 256 + (((gk) ^ ((pq + 2) & 7)) << 2) + kq] = v.z;
        w2t[(pq + 3) * 256 + (((gk) ^ ((pq + 3) & 7)) << 2) + kq] = v.w;
    }
    __syncthreads();

    const int rg = tid & 15;
    const int cg = tid >> 4;
    float acc[2][16];
    #pragma unroll
    for (int j = 0; j < 2; ++j)
        #pragma unroll
        for (int i = 0; i < 16; ++i) acc[j][i] = 0.0f;

    const float* w1p = W1 + (size_t)(r * D_TOT) * H_TOT + (cg << 4);
    #pragma unroll 4
    for (int d = 0; d <= r; ++d) {
        float2 zv = *reinterpret_cast<const float2*>(&z_t[d * 32 + (rg << 1)]);
        const float* wrow = w1p + (size_t)d * H_TOT;
        float wv[16];
        *reinterpret_cast<float4*>(&wv[0])  = *reinterpret_cast<const float4*>(wrow + 0);
        *reinterpret_cast<float4*>(&wv[4])  = *reinterpret_cast<const float4*>(wrow + 4);
        *reinterpret_cast<float4*>(&wv[8])  = *reinterpret_cast<const float4*>(wrow + 8);
        *reinterpret_cast<float4*>(&wv[12]) = *reinterpret_cast<const float4*>(wrow + 12);
        #pragma unroll
        for (int i = 0; i < 16; ++i) {
            acc[0][i] = fmaf(zv.x, wv[i], acc[0][i]);
            acc[1][i] = fmaf(zv.y, wv[i], acc[1][i]);
        }
    }
    {
        const int key = (rg >> 1) & 7;
        #pragma unroll
        for (int gi = 0; gi < 4; ++gi) {
            float4 bv = *reinterpret_cast<const float4*>(&b1[(size_t)r * H_TOT + (cg << 4) + (gi << 2)]);
            #pragma unroll
            for (int j = 0; j < 2; ++j) {
                float4 v;
                v.x = fmaxf(acc[j][4 * gi + 0] + bv.x, 0.0f);
                v.y = fmaxf(acc[j][4 * gi + 1] + bv.y, 0.0f);
                v.z = fmaxf(acc[j][4 * gi + 2] + bv.z, 0.0f);
                v.w = fmaxf(acc[j][4 * gi + 3] + bv.w, 0.0f);
                int bb = (rg << 1) + j;
                int g  = ((cg << 2) + gi) ^ key;
                *reinterpret_cast<float4*>(&h_s[bb * 256 + (g << 2)]) = v;
            }
        }
    }
    __syncthreads();

    const int wv_ = tid >> 6;
    const int ln  = tid & 63;
    const int bq  = ln & 7;
    const int pg  = ln >> 3;
    float acc2[4][3];
    #pragma unroll
    for (int j = 0; j < 4; ++j)
        #pragma unroll
        for (int i = 0; i < 3; ++i) acc2[j][i] = 0.0f;

    #pragma unroll
    for (int c = 0; c < 8; ++c) {
        int k0  = (wv_ << 6) + (c << 3);
        int gk0 = k0 >> 2;
        float w2r[3][8], hr[4][8];
        #pragma unroll
        for (int i = 0; i < 3; ++i) {
            int p = 3 * pg + i, pk = p & 7;
            *reinterpret_cast<float4*>(&w2r[i][0]) =
                *reinterpret_cast<const float4*>(&w2t[p * 256 + (((gk0 + 0) ^ pk) << 2)]);
            *reinterpret_cast<float4*>(&w2r[i][4]) =
                *reinterpret_cast<const float4*>(&w2t[p * 256 + (((gk0 + 1) ^ pk) << 2)]);
        }
        #pragma unroll
        for (int j = 0; j < 4; ++j) {
            int bb = 4 * bq + j;
            *reinterpret_cast<float4*>(&hr[j][0]) =
                *reinterpret_cast<const float4*>(&h_s[bb * 256 + (((gk0 + 0) ^ bq) << 2)]);
            *reinterpret_cast<float4*>(&hr[j][4]) =
                *reinterpret_cast<const float4*>(&h_s[bb * 256 + (((gk0 + 1) ^ bq) << 2)]);
        }
        #pragma unroll
        for (int kk = 0; kk < 8; ++kk)
            #pragma unroll
            for (int j = 0; j < 4; ++j)
                #pragma unroll
                for (int i = 0; i < 3; ++i)
                    acc2[j][i] = fmaf(hr[j][kk], w2r[i][kk], acc2[j][i]);
    }
    __syncthreads();
    #pragma unroll
    for (int j = 0; j < 4; ++j)
        #pragma unroll
        for (int i = 0; i < 3; ++i)
            part[((wv_ << 5) + 4 * bq + j) * PK_TOT + 3 * pg + i] = acc2[j][i];
    __syncthreads();

    {
        const int eb = tid >> 3;
        const int ej = tid & 7;
        float rawa = b2[(size_t)r * PK_TOT + ej];
        float rawb = b2[(size_t)r * PK_TOT + 8 + ej];
        float rawr = b2[(size_t)r * PK_TOT + 16 + ej];
        #pragma unroll
        for (int w = 0; w < 4; ++w) {
            rawa += part[((w << 5) + eb) * PK_TOT + ej];
            rawb += part[((w << 5) + eb) * PK_TOT + 8 + ej];
            rawr += part[((w << 5) + eb) * PK_TOT + 16 + ej];
        }
        float zi = z_t[(r + 1) * 32 + eb];
        float t  = tanf((zi - PI_F) * 0.5f);
        float al = expf(rawa);
        float g  = fmaf(al, t, rawb);
        float X  = 2.0f * atanf(g) + PI_F;
        float dv = al * (1.0f + t * t) / (1.0f + g * g);
        float m = rawr;
        m = fmaxf(m, __shfl_xor(m, 1));
        m = fmaxf(m, __shfl_xor(m, 2));
        m = fmaxf(m, __shfl_xor(m, 4));
        float e  = expf(rawr - m);
        float se = e, sx = e * X, sd = e * dv;
        se += __shfl_xor(se, 1); se += __shfl_xor(se, 2); se += __shfl_xor(se, 4);
        sx += __shfl_xor(sx, 1); sx += __shfl_xor(sx, 2); sx += __shfl_xor(sx, 4);
        sd += __shfl_xor(sd, 1); sd += __shfl_xor(sd, 2); sd += __shfl_xor(sd, 4);
        if (ej == 0) {
            int gb = b0 + eb;
            out[(size_t)gb * D_TOT + (r + 1)] = sx / se;
            atomicAdd(&out[(size_t)B_TOT * D_TOT + gb], logf(sd / se));
        }
    }
}

extern "C" void kernel_launch(void* const* d_in, const int* in_sizes, int n_in,
                              void* d_out, int out_size, void* d_ws, size_t ws_size,
                              hipStream_t stream) {
    const float* z  = (const float*)d_in[0];
    const float* W1 = (const float*)d_in[1];
    const float* b1 = (const float*)d_in[2];
    const float* W2 = (const float*)d_in[3];
    const float* b2 = (const float*)d_in[4];
    float* out = (float*)d_out;

    init_out_kernel<<<dim3(B_TOT / 256), dim3(256), 0, stream>>>(out);
    if (ws_size >= (size_t)WS_NEED) {
        prep_weights<<<dim3(756), dim3(256), 0, stream>>>(W1, W2, (unsigned int*)d_ws);
        flow_mfma<<<dim3(B_TOT / 64, R_TOT), dim3(256), 0, stream>>>(
            z, (const unsigned int*)d_ws, b1, b2, out);
    } else {
        flow_fp32<<<dim3(B_TOT / 32, R_TOT), dim3(256), 0, stream>>>(z, W1, b1, W2, b2, out);
    }
}

// Round 4
// 182.882 us; speedup vs baseline: 3.8663x; 1.0602x over previous
//
#include <hip/hip_runtime.h>
#include <math.h>
#include <type_traits>

typedef __bf16 bf16x8 __attribute__((ext_vector_type(8)));
typedef float f32x4 __attribute__((ext_vector_type(4)));
typedef unsigned int u32x4 __attribute__((ext_vector_type(4)));

#define B_TOT 16384
#define D_TOT 64
#define R_TOT 63
#define H_TOT 256
#define PK_TOT 24
#define PI_F 3.14159265358979323846f

// ws layout: W1F fragments then W2F fragments (u32 units)
#define W2F_BASE_U32 1032192u
#define WS_NEED 6193152u

#define MFMA16(a, b, c) __builtin_amdgcn_mfma_f32_16x16x32_bf16((a), (b), (c), 0, 0, 0)

__device__ __forceinline__ unsigned short bf16_rtne(float f) {
    unsigned u = __float_as_uint(f);
    unsigned rr = u + 0x7FFFu + ((u >> 16) & 1u);
    return (unsigned short)(rr >> 16);
}

// one v_cvt_pk_bf16_f32: packs rtne(a) | rtne(b)<<16 (no builtin on gfx950)
__device__ __forceinline__ unsigned cvt_pk_bf16(float a, float b) {
    unsigned r;
    asm("v_cvt_pk_bf16_f32 %0, %1, %2" : "=v"(r) : "v"(a), "v"(b));
    return r;
}

// split 4 f32 -> hi plane (truncated bf16 x4) + lo plane (rtne residual x4)
__device__ __forceinline__ void split4(const float* v, uint2& hi, uint2& lo) {
    unsigned u0 = __float_as_uint(v[0]), u1 = __float_as_uint(v[1]);
    unsigned u2 = __float_as_uint(v[2]), u3 = __float_as_uint(v[3]);
    hi.x = __builtin_amdgcn_perm(u1, u0, 0x07060302u);   // {u1.hi16, u0.hi16}
    hi.y = __builtin_amdgcn_perm(u3, u2, 0x07060302u);
    float r0 = v[0] - __uint_as_float(u0 & 0xFFFF0000u);
    float r1 = v[1] - __uint_as_float(u1 & 0xFFFF0000u);
    float r2 = v[2] - __uint_as_float(u2 & 0xFFFF0000u);
    float r3 = v[3] - __uint_as_float(u3 & 0xFFFF0000u);
    lo.x = cvt_pk_bf16(r0, r1);
    lo.y = cvt_pk_bf16(r2, r3);
}

__global__ void init_out_kernel(float* __restrict__ out) {
    int b = blockIdx.x * 256 + threadIdx.x;
    if (b < B_TOT) {
        out[(size_t)b * D_TOT] = 0.0f;            // x[:,0] = 0
        out[(size_t)B_TOT * D_TOT + b] = 0.0f;    // log_det = 0
    }
}

// ---------------- prep: weights -> split-bf16 MFMA fragments in ws ----------------
// Bias trick: b1[r] is stored in the free padded K-row (d=31 for r<=30, d=63 for r>=31);
// the main kernel forces the staged z at that row to 1.0, so GEMM1 emits z*W1m + b1.
__global__ void prep_weights(const float* __restrict__ W1,
                             const float* __restrict__ b1,
                             const float* __restrict__ W2,
                             unsigned int* __restrict__ wsf)
{
    int gid = blockIdx.x * 256 + threadIdx.x;
    if (gid >= 193536) return;
    float v[8];
    unsigned int* dst;
    if (gid < 129024) {
        int lane = gid & 63;
        int q = gid >> 6;
        int t = q & 1; q >>= 1;
        int nt = q & 15; int r = q >> 4;
        int n  = (nt << 4) + (lane & 15);
        int kb = (t << 5) + ((lane >> 4) << 3);
        int bias_d = (r <= 30) ? 31 : 63;
        #pragma unroll
        for (int j = 0; j < 8; ++j) {
            int d = kb + j;
            v[j] = (d <= r) ? W1[(size_t)(r * 64 + d) * 256 + n]
                 : (d == bias_d ? b1[(size_t)r * 256 + n] : 0.0f);
        }
        int frag = ((r * 16 + nt) * 2 + t) * 2;
        dst = wsf + ((size_t)frag * 64 + lane) * 4;
    } else {
        int g2 = gid - 129024;
        int lane = g2 & 63;
        int q = g2 >> 6;
        int ks = q & 7; q >>= 3;
        int nt = q & 1; int r = q >> 1;
        int n  = (nt << 4) + (lane & 15);
        int kb = (ks << 5) + ((lane >> 4) << 3);
        #pragma unroll
        for (int j = 0; j < 8; ++j) {
            int k = kb + j;
            v[j] = (n < PK_TOT) ? W2[(size_t)(r * 256 + k) * PK_TOT + n] : 0.0f;
        }
        int frag = ((r * 2 + nt) * 8 + ks) * 2;
        dst = wsf + W2F_BASE_U32 + ((size_t)frag * 64 + lane) * 4;
    }
    unsigned hw[4], lw[4];
    #pragma unroll
    for (int i = 0; i < 4; ++i) {
        float a = v[2 * i], b = v[2 * i + 1];
        unsigned ua = __float_as_uint(a), ub = __float_as_uint(b);
        float ra = a - __uint_as_float(ua & 0xFFFF0000u);
        float rb = b - __uint_as_float(ub & 0xFFFF0000u);
        hw[i] = (ua >> 16) | (ub & 0xFFFF0000u);
        lw[i] = (unsigned)bf16_rtne(ra) | ((unsigned)bf16_rtne(rb) << 16);
    }
    *reinterpret_cast<u32x4*>(dst)       = u32x4{hw[0], hw[1], hw[2], hw[3]};
    *reinterpret_cast<u32x4*>(dst + 256) = u32x4{lw[0], lw[1], lw[2], lw[3]};
}

// ---------------- main MFMA kernel: block = 64 batches x one r, 4 waves ----------------
// 48 KB LDS + 80 VGPR -> 3 blocks/CU (launch_bounds min 3 waves/EU).
__global__ __launch_bounds__(256, 3) void flow_mfma(
    const float* __restrict__ z, const unsigned int* __restrict__ wsf,
    const float* __restrict__ b2, float* __restrict__ out)
{
    const int r   = blockIdx.y;
    const int b0  = blockIdx.x << 6;
    const int tid = threadIdx.x;
    const int w   = tid >> 6;
    const int l   = tid & 63;
    const int l15 = l & 15, l4 = l >> 4, key = l & 7;

    __shared__ __align__(16) unsigned char sm[49152];

    // ---- stage z split (hi trunc / lo rtne); bias row forced to 1.0 ----
    {
        const int m  = tid >> 2;
        const int dq = (tid & 3) << 4;
        const float* zp = z + (size_t)(b0 + m) * 64 + dq;
        const int mkey = m & 7;
        const int bias_d = (r <= 30) ? 31 : 63;
        const int rel = bias_d - dq;            // in [0,16) only for the owning thread
        #pragma unroll
        for (int qq = 0; qq < 4; ++qq) {
            float4 val = *reinterpret_cast<const float4*>(zp + (qq << 2));
            int d0 = dq + (qq << 2);
            float vv[4] = {val.x, val.y, val.z, val.w};
            if ((rel >> 2) == qq) vv[rel & 3] = 1.0f;   // bias row -> 1.0 (exact split)
            uint2 hi, lo;
            split4(vv, hi, lo);
            int off = (m << 7) + ((((d0 >> 3)) ^ mkey) << 4) + (((d0 >> 2) & 1) << 3);
            *reinterpret_cast<uint2*>(sm + off) = hi;
            *reinterpret_cast<uint2*>(sm + 8192 + off) = lo;
        }
    }
    __syncthreads();

    // ---- GEMM1 (output-transposed): D1[n][m] = sum_d W1m[d][n] * z[m][d] (+ b1 via bias row) ----
    f32x4 acc1[4][4];     // [ntl][mt]
    #pragma unroll
    for (int a = 0; a < 4; ++a)
        #pragma unroll
        for (int b = 0; b < 4; ++b) acc1[a][b] = f32x4{0.f, 0.f, 0.f, 0.f};

    auto run_gemm1 = [&](auto FULLC) {
        constexpr bool FULL = decltype(FULLC)::value;
        constexpr int NT = FULL ? 2 : 1;
        bf16x8 zf[4][NT][2];   // [mt][t][plane]
        #pragma unroll
        for (int mt = 0; mt < 4; ++mt)
            #pragma unroll
            for (int t = 0; t < NT; ++t) {
                int m = (mt << 4) + l15;
                int off = (m << 7) + ((((t << 2) + l4) ^ key) << 4);
                zf[mt][t][0] = __builtin_bit_cast(bf16x8, *reinterpret_cast<u32x4*>(sm + off));
                zf[mt][t][1] = __builtin_bit_cast(bf16x8, *reinterpret_cast<u32x4*>(sm + 8192 + off));
            }
        const unsigned int* w1b = wsf + (size_t)((r * 16 + (w << 2)) * 4) * 256 + (l << 2);
        #pragma unroll
        for (int ntl = 0; ntl < 4; ++ntl) {
            bf16x8 af[NT][2];
            #pragma unroll
            for (int t = 0; t < NT; ++t)
                #pragma unroll
                for (int pl = 0; pl < 2; ++pl)
                    af[t][pl] = __builtin_bit_cast(bf16x8,
                        *reinterpret_cast<const u32x4*>(w1b + ((ntl * 4 + t * 2 + pl) << 8)));
            #pragma unroll
            for (int t = 0; t < NT; ++t) {
                #pragma unroll
                for (int mt = 0; mt < 4; ++mt)
                    acc1[ntl][mt] = MFMA16(af[t][0], zf[mt][t][0], acc1[ntl][mt]);
                #pragma unroll
                for (int mt = 0; mt < 4; ++mt)
                    acc1[ntl][mt] = MFMA16(af[t][0], zf[mt][t][1], acc1[ntl][mt]);
                #pragma unroll
                for (int mt = 0; mt < 4; ++mt)
                    acc1[ntl][mt] = MFMA16(af[t][1], zf[mt][t][0], acc1[ntl][mt]);
            }
        }
    };
    if (r >= 31) run_gemm1(std::true_type{});
    else         run_gemm1(std::false_type{});

    // relu + split-bf16, write this wave's 64 h-columns into the half-tile (bias already in acc)
    auto write_h = [&]() {
        #pragma unroll
        for (int ntl = 0; ntl < 4; ++ntl) {
            #pragma unroll
            for (int mt = 0; mt < 4; ++mt) {
                float vv[4];
                #pragma unroll
                for (int i = 0; i < 4; ++i)
                    vv[i] = fmaxf(acc1[ntl][mt][i], 0.0f);
                uint2 hi, lo;
                split4(vv, hi, lo);
                int m   = (mt << 4) + l15;
                int gl  = ((w & 1) << 3) + (ntl << 1) + (l4 >> 1);
                int off = (m << 8) + ((gl ^ key) << 4) + ((l4 & 1) << 3);
                *reinterpret_cast<uint2*>(sm + 16384 + off) = hi;
                *reinterpret_cast<uint2*>(sm + 32768 + off) = lo;
            }
        }
    };

    f32x4 acc2[2][4];     // [nt2][mt]  D2[n][m] = sum_k W2[k][n] h[m][k]
    #pragma unroll
    for (int a = 0; a < 2; ++a)
        #pragma unroll
        for (int b = 0; b < 4; ++b) acc2[a][b] = f32x4{0.f, 0.f, 0.f, 0.f};

    const unsigned int* w2b = wsf + W2F_BASE_U32 + (size_t)(r * 32) * 256 + (l << 2);
    auto gemm2 = [&](int p) {
        const int ks = (p << 2) + w;   // wave's global k-step (32 k each)
        bf16x8 wf[2][2];
        #pragma unroll
        for (int nt2 = 0; nt2 < 2; ++nt2)
            #pragma unroll
            for (int pl = 0; pl < 2; ++pl)
                wf[nt2][pl] = __builtin_bit_cast(bf16x8,
                    *reinterpret_cast<const u32x4*>(w2b + ((nt2 * 16 + ks * 2 + pl) << 8)));
        bf16x8 hfr[4][2];
        #pragma unroll
        for (int mt = 0; mt < 4; ++mt) {
            int m   = (mt << 4) + l15;
            int off = (m << 8) + ((((w << 2) + l4) ^ key) << 4);
            hfr[mt][0] = __builtin_bit_cast(bf16x8, *reinterpret_cast<u32x4*>(sm + 16384 + off));
            hfr[mt][1] = __builtin_bit_cast(bf16x8, *reinterpret_cast<u32x4*>(sm + 32768 + off));
        }
        #pragma unroll
        for (int nt2 = 0; nt2 < 2; ++nt2)
            #pragma unroll
            for (int mt = 0; mt < 4; ++mt)
                acc2[nt2][mt] = MFMA16(wf[nt2][0], hfr[mt][0], acc2[nt2][mt]);
        #pragma unroll
        for (int nt2 = 0; nt2 < 2; ++nt2)
            #pragma unroll
            for (int mt = 0; mt < 4; ++mt)
                acc2[nt2][mt] = MFMA16(wf[nt2][0], hfr[mt][1], acc2[nt2][mt]);
        #pragma unroll
        for (int nt2 = 0; nt2 < 2; ++nt2)
            #pragma unroll
            for (int mt = 0; mt < 4; ++mt)
                acc2[nt2][mt] = MFMA16(wf[nt2][1], hfr[mt][0], acc2[nt2][mt]);
    };

    if (w < 2) write_h();       // waves 0,1 own h-cols 0..127
    __syncthreads();
    gemm2(0);                   // k = 0..127
    __syncthreads();
    if (w >= 2) write_h();      // h-cols 128..255 overwrite the half-tile
    __syncthreads();
    gemm2(1);                   // k = 128..255

    // ---- cross-wave reduce of raw via LDS (aliases dead z region) ----
    auto part_off = [&](int ph, int nt2, int mt) -> int {
        int m = (mt << 4) + l15;
        return (((ph << 6) + m) << 7) + ((((nt2 << 2) + l4) ^ key) << 4);
    };
    if (w < 2) {
        #pragma unroll
        for (int nt2 = 0; nt2 < 2; ++nt2)
            #pragma unroll
            for (int mt = 0; mt < 4; ++mt)
                *reinterpret_cast<f32x4*>(sm + part_off(w, nt2, mt)) = acc2[nt2][mt];
    }
    __syncthreads();
    if (w >= 2) {
        #pragma unroll
        for (int nt2 = 0; nt2 < 2; ++nt2)
            #pragma unroll
            for (int mt = 0; mt < 4; ++mt) {
                f32x4* p = reinterpret_cast<f32x4*>(sm + part_off(w - 2, nt2, mt));
                *p = *p + acc2[nt2][mt];
            }
    }
    __syncthreads();

    // ---- flow epilogue (fast transcendentals) ----
    #pragma unroll
    for (int mh = 0; mh < 2; ++mh) {
        const int m  = (mh << 5) + (tid >> 3);
        const int j  = tid & 7;
        const int mk = m & 7;
        float ra = b2[(size_t)r * 24 + j];
        float rb = b2[(size_t)r * 24 + 8 + j];
        float rr = b2[(size_t)r * 24 + 16 + j];
        #pragma unroll
        for (int ph = 0; ph < 2; ++ph) {
            const int base = (((ph << 6) + m) << 7);
            const int sub  = (j & 3) << 2;
            ra += *reinterpret_cast<float*>(sm + base + ((((j) >> 2) ^ mk) << 4) + sub);
            rb += *reinterpret_cast<float*>(sm + base + ((((8 + j) >> 2) ^ mk) << 4) + sub);
            rr += *reinterpret_cast<float*>(sm + base + ((((16 + j) >> 2) ^ mk) << 4) + sub);
        }
        float zi = z[(size_t)(b0 + m) * 64 + r + 1];
        // tan((zi - pi)/2) == -cos(zi/2)/sin(zi/2); clamp to avoid inf^2/inf^2 NaN at zi=0
        float s, c;
        __sincosf(zi * 0.5f, &s, &c);
        float t = -c * __builtin_amdgcn_rcpf(s);
        t = fminf(fmaxf(t, -1e8f), 1e8f);
        float al = __expf(ra);
        float g  = fmaf(al, t, rb);
        float X  = 2.0f * atanf(g) + PI_F;
        float dv = al * fmaf(t, t, 1.0f) * __builtin_amdgcn_rcpf(fmaf(g, g, 1.0f));
        float mx = rr;
        mx = fmaxf(mx, __shfl_xor(mx, 1));
        mx = fmaxf(mx, __shfl_xor(mx, 2));
        mx = fmaxf(mx, __shfl_xor(mx, 4));
        float e = __expf(rr - mx);
        float se = e, sx = e * X, sd = e * dv;
        se += __shfl_xor(se, 1); se += __shfl_xor(se, 2); se += __shfl_xor(se, 4);
        sx += __shfl_xor(sx, 1); sx += __shfl_xor(sx, 2); sx += __shfl_xor(sx, 4);
        sd += __shfl_xor(sd, 1); sd += __shfl_xor(sd, 2); sd += __shfl_xor(sd, 4);
        if (j == 0) {
            int gb = b0 + m;
            float rse = __builtin_amdgcn_rcpf(se);
            out[(size_t)gb * D_TOT + r + 1] = sx * rse;
            atomicAdd(&out[(size_t)B_TOT * D_TOT + gb], __logf(sd * rse));
        }
    }
}

// ---------------- fp32 fallback (round-1 kernel, known-correct) ----------------
__global__ __launch_bounds__(256, 2) void flow_fp32(
    const float* __restrict__ z,  const float* __restrict__ W1,
    const float* __restrict__ b1, const float* __restrict__ W2,
    const float* __restrict__ b2, float* __restrict__ out)
{
    const int r   = blockIdx.y;
    const int b0  = blockIdx.x * 32;
    const int tid = threadIdx.x;

    __shared__ float smem[16384];
    float* z_t  = smem;
    float* h_s  = smem + 2048;
    float* w2t  = smem + 2048 + 8192;
    float* part = w2t;

    #pragma unroll
    for (int it = 0; it < 2; ++it) {
        int idx4 = it * 256 + tid;
        int brow = idx4 >> 4;
        int dq   = (idx4 & 15) << 2;
        float4 v = *reinterpret_cast<const float4*>(&z[(size_t)(b0 + brow) * D_TOT + dq]);
        z_t[(dq + 0) * 32 + brow] = v.x;
        z_t[(dq + 1) * 32 + brow] = v.y;
        z_t[(dq + 2) * 32 + brow] = v.z;
        z_t[(dq + 3) * 32 + brow] = v.w;
    }
    #pragma unroll
    for (int it = 0; it < 6; ++it) {
        int idx4 = it * 256 + tid;
        int k  = idx4 / 6;
        int pq = (idx4 - k * 6) << 2;
        float4 v = *reinterpret_cast<const float4*>(&W2[(size_t)(r * H_TOT + k) * PK_TOT + pq]);
        int gk = k >> 2, kq = k & 3;
        w2t[(pq + 0) * 256 + (((gk) ^ ((pq + 0) & 7)) << 2) + kq] = v.x;
        w2t[(pq + 1) * 256 + (((gk) ^ ((pq + 1) & 7)) << 2) + kq] = v.y;
        w2t[(pq + 2) * 256 + (((gk) ^ ((pq + 2) & 7)) << 2) + kq] = v.z;
        w2t[(pq + 3) * 256 + (((gk) ^ ((pq + 3) & 7)) << 2) + kq] = v.w;
    }
    __syncthreads();

    const int rg = tid & 15;
    const int cg = tid >> 4;
    float acc[2][16];
    #pragma unroll
    for (int j = 0; j < 2; ++j)
        #pragma unroll
        for (int i = 0; i < 16; ++i) acc[j][i] = 0.0f;

    const float* w1p = W1 + (size_t)(r * D_TOT) * H_TOT + (cg << 4);
    #pragma unroll 4
    for (int d = 0; d <= r; ++d) {
        float2 zv = *reinterpret_cast<const float2*>(&z_t[d * 32 + (rg << 1)]);
        const float* wrow = w1p + (size_t)d * H_TOT;
        float wv[16];
        *reinterpret_cast<float4*>(&wv[0])  = *reinterpret_cast<const float4*>(wrow + 0);
        *reinterpret_cast<float4*>(&wv[4])  = *reinterpret_cast<const float4*>(wrow + 4);
        *reinterpret_cast<float4*>(&wv[8])  = *reinterpret_cast<const float4*>(wrow + 8);
        *reinterpret_cast<float4*>(&wv[12]) = *reinterpret_cast<const float4*>(wrow + 12);
        #pragma unroll
        for (int i = 0; i < 16; ++i) {
            acc[0][i] = fmaf(zv.x, wv[i], acc[0][i]);
            acc[1][i] = fmaf(zv.y, wv[i], acc[1][i]);
        }
    }
    {
        const int key = (rg >> 1) & 7;
        #pragma unroll
        for (int gi = 0; gi < 4; ++gi) {
            float4 bv = *reinterpret_cast<const float4*>(&b1[(size_t)r * H_TOT + (cg << 4) + (gi << 2)]);
            #pragma unroll
            for (int j = 0; j < 2; ++j) {
                float4 v;
                v.x = fmaxf(acc[j][4 * gi + 0] + bv.x, 0.0f);
                v.y = fmaxf(acc[j][4 * gi + 1] + bv.y, 0.0f);
                v.z = fmaxf(acc[j][4 * gi + 2] + bv.z, 0.0f);
                v.w = fmaxf(acc[j][4 * gi + 3] + bv.w, 0.0f);
                int bb = (rg << 1) + j;
                int g  = ((cg << 2) + gi) ^ key;
                *reinterpret_cast<float4*>(&h_s[bb * 256 + (g << 2)]) = v;
            }
        }
    }
    __syncthreads();

    const int wv_ = tid >> 6;
    const int ln  = tid & 63;
    const int bq  = ln & 7;
    const int pg  = ln >> 3;
    float acc2[4][3];
    #pragma unroll
    for (int j = 0; j < 4; ++j)
        #pragma unroll
        for (int i = 0; i < 3; ++i) acc2[j][i] = 0.0f;

    #pragma unroll
    for (int c = 0; c < 8; ++c) {
        int k0  = (wv_ << 6) + (c << 3);
        int gk0 = k0 >> 2;
        float w2r[3][8], hr[4][8];
        #pragma unroll
        for (int i = 0; i < 3; ++i) {
            int p = 3 * pg + i, pk = p & 7;
            *reinterpret_cast<float4*>(&w2r[i][0]) =
                *reinterpret_cast<const float4*>(&w2t[p * 256 + (((gk0 + 0) ^ pk) << 2)]);
            *reinterpret_cast<float4*>(&w2r[i][4]) =
                *reinterpret_cast<const float4*>(&w2t[p * 256 + (((gk0 + 1) ^ pk) << 2)]);
        }
        #pragma unroll
        for (int j = 0; j < 4; ++j) {
            int bb = 4 * bq + j;
            *reinterpret_cast<float4*>(&hr[j][0]) =
                *reinterpret_cast<const float4*>(&h_s[bb * 256 + (((gk0 + 0) ^ bq) << 2)]);
            *reinterpret_cast<float4*>(&hr[j][4]) =
                *reinterpret_cast<const float4*>(&h_s[bb * 256 + (((gk0 + 1) ^ bq) << 2)]);
        }
        #pragma unroll
        for (int kk = 0; kk < 8; ++kk)
            #pragma unroll
            for (int j = 0; j < 4; ++j)
                #pragma unroll
                for (int i = 0; i < 3; ++i)
                    acc2[j][i] = fmaf(hr[j][kk], w2r[i][kk], acc2[j][i]);
    }
    __syncthreads();
    #pragma unroll
    for (int j = 0; j < 4; ++j)
        #pragma unroll
        for (int i = 0; i < 3; ++i)
            part[((wv_ << 5) + 4 * bq + j) * PK_TOT + 3 * pg + i] = acc2[j][i];
    __syncthreads();

    {
        const int eb = tid >> 3;
        const int ej = tid & 7;
        float rawa = b2[(size_t)r * PK_TOT + ej];
        float rawb = b2[(size_t)r * PK_TOT + 8 + ej];
        float rawr = b2[(size_t)r * PK_TOT + 16 + ej];
        #pragma unroll
        for (int w = 0; w < 4; ++w) {
            rawa += part[((w << 5) + eb) * PK_TOT + ej];
            rawb += part[((w << 5) + eb) * PK_TOT + 8 + ej];
            rawr += part[((w << 5) + eb) * PK_TOT + 16 + ej];
        }
        float zi = z_t[(r + 1) * 32 + eb];
        float t  = tanf((zi - PI_F) * 0.5f);
        float al = expf(rawa);
        float g  = fmaf(al, t, rawb);
        float X  = 2.0f * atanf(g) + PI_F;
        float dv = al * (1.0f + t * t) / (1.0f + g * g);
        float m = rawr;
        m = fmaxf(m, __shfl_xor(m, 1));
        m = fmaxf(m, __shfl_xor(m, 2));
        m = fmaxf(m, __shfl_xor(m, 4));
        float e  = expf(rawr - m);
        float se = e, sx = e * X, sd = e * dv;
        se += __shfl_xor(se, 1); se += __shfl_xor(se, 2); se += __shfl_xor(se, 4);
        sx += __shfl_xor(sx, 1); sx += __shfl_xor(sx, 2); sx += __shfl_xor(sx, 4);
        sd += __shfl_xor(sd, 1); sd += __shfl_xor(sd, 2); sd += __shfl_xor(sd, 4);
        if (ej == 0) {
            int gb = b0 + eb;
            out[(size_t)gb * D_TOT + (r + 1)] = sx / se;
            atomicAdd(&out[(size_t)B_TOT * D_TOT + gb], logf(sd / se));
        }
    }
}

extern "C" void kernel_launch(void* const* d_in, const int* in_sizes, int n_in,
                              void* d_out, int out_size, void* d_ws, size_t ws_size,
                              hipStream_t stream) {
    const float* z  = (const float*)d_in[0];
    const float* W1 = (const float*)d_in[1];
    const float* b1 = (const float*)d_in[2];
    const float* W2 = (const float*)d_in[3];
    const float* b2 = (const float*)d_in[4];
    float* out = (float*)d_out;

    init_out_kernel<<<dim3(B_TOT / 256), dim3(256), 0, stream>>>(out);
    if (ws_size >= (size_t)WS_NEED) {
        prep_weights<<<dim3(756), dim3(256), 0, stream>>>(W1, b1, W2, (unsigned int*)d_ws);
        flow_mfma<<<dim3(B_TOT / 64, R_TOT), dim3(256), 0, stream>>>(
            z, (const unsigned int*)d_ws, b2, out);
    } else {
        flow_fp32<<<dim3(B_TOT / 32, R_TOT), dim3(256), 0, stream>>>(z, W1, b1, W2, b2, out);
    }
}